// Round 17
// baseline (380.755 us; speedup 1.0000x reference)
//
#include <hip/hip_runtime.h>
#include <math.h>

#define L_TOT 36864
#define BN_EPS 1e-5f
#define PCH 45000   // padded channel stride: 18*50*50

#define NCH1 768
#define LCH1 48
#define NCH2 1152
#define LCH2 32

typedef __attribute__((ext_vector_type(8))) short bf16x8;
typedef __attribute__((ext_vector_type(4))) float f32x4;

__device__ __forceinline__ float fsigmoid(float x){ return 1.f/(1.f+__expf(-x)); }
__device__ __forceinline__ float fsoftplus(float x){
  float e = __expf(x);
  return (x>20.f)? x : __logf(1.f+e);
}
__device__ __forceinline__ unsigned short f2bf(float x){
  union { float f; unsigned u; } cv; cv.f = x;
  unsigned r = (cv.u + 0x7FFFu + ((cv.u>>16)&1u)) >> 16;
  return (unsigned short)r;
}
__host__ __device__ constexpr int off3c(int r){
  return (r>=27) ? 0 : ((r/9)-1)*2500 + (((r%9)/3)-1)*50 + ((r%3)-1);
}

// ---------------- zero-fill (32-bit words) ----------------------------------------
__global__ void k_zero(float* __restrict__ p, int n) {
  int i = blockIdx.x*256 + threadIdx.x;
  if (i < n) p[i] = 0.f;
}

// ---------------- setup: pack both conv weights (bf16 A-fragments) + zero stats ---
__global__ void k_setup(const float* __restrict__ w1, unsigned short* __restrict__ wA1,
                        const float* __restrict__ w2, unsigned short* __restrict__ wA2,
                        float* __restrict__ stats) {
  int b = blockIdx.x, tid = threadIdx.x;
  if (b < 4){
    int k = b*256 + tid;
    if (k < 864){
      int ic = k & 31, r = k >> 5;
      for (int m=0;m<16;m++){
        float v = (r < 27) ? w1[m*32*27 + ic*27 + r] : 0.f;
        wA1[(((k>>3)*16) + m)*8 + (k&7)] = f2bf(v);
      }
    }
  } else {
    int k = (b-4)*256 + tid;
    if (k < 448){
      int ic = k & 15, r = k >> 4;
      for (int m=0;m<16;m++){
        float v = (r < 27) ? w2[m*16*27 + ic*27 + r] : 0.f;
        wA2[(((k>>3)*16) + m)*8 + (k&7)] = f2bf(v);
      }
    }
    if (b==5 && tid>=192) stats[tid-192] = 0.f;
  }
}

// ---------------- in-proj with fused LayerNorm, NU rows per thread ----------------
template<int DIM, int DI, bool DOBN, int NU>
__global__ __launch_bounds__(256) void k_inproj(const float* __restrict__ x0, const float* __restrict__ x1,
                         const float* __restrict__ bstats, const float* __restrict__ bg,
                         const float* __restrict__ bb,
                         const float* __restrict__ lnw, const float* __restrict__ lnb,
                         const float* __restrict__ inw,
                         float* __restrict__ xs, float* __restrict__ z) {
  int t = blockIdx.x*64 + threadIdx.x;
  int j0 = (blockIdx.y*4 + threadIdx.y)*NU;
  float xv[DIM];
  float s=0.f, s2=0.f;
#pragma unroll
  for (int c=0;c<DIM;c++){
    float v = (c<16)? x0[c*L_TOT+t] : x1[(c-16)*L_TOT+t];
    if (DOBN){
      float bm = bstats[2*c]*(1.f/L_TOT);
      float bv = bstats[2*c+1]*(1.f/L_TOT) - bm*bm;
      v = (v-bm)*rsqrtf(bv+BN_EPS)*bg[c] + bb[c];
    }
    xv[c]=v; s += v; s2 += v*v;
  }
  float m = s*(1.f/DIM);
  float var = s2*(1.f/DIM) - m*m;
  float rs = rsqrtf(var + BN_EPS);
  float a[NU];
#pragma unroll
  for (int u=0;u<NU;u++) a[u]=0.f;
#pragma unroll
  for (int c=0;c<DIM;c++){
    float xn = (xv[c]-m)*rs*lnw[c] + lnb[c];
#pragma unroll
    for (int u=0;u<NU;u++) a[u] += xn*inw[(j0+u)*DIM+c];
  }
#pragma unroll
  for (int u=0;u<NU;u++){
    int j=j0+u;
    if (j<DI) xs[j*L_TOT+t]=a[u]; else z[(j-DI)*L_TOT+t]=a[u];
  }
}

// ---------------- fused depthwise-conv + SiLU + x-proj (LDS-resident) -------------
// block 64x4. Phase1: stage xs window [t0-3,t0+64) for all DI rows in LDS.
// Phase2: causal conv+SiLU per (row,t) -> write xc global, overwrite LDS tile.
// Phase3: x-proj rows from LDS (weights wave-uniform via ty -> s_load).
template<int DI, int DTR>
__global__ __launch_bounds__(256) void k_dwxp(const float* __restrict__ xs,
                        const float* __restrict__ cw, const float* __restrict__ cb,
                        const float* __restrict__ xpw,
                        float* __restrict__ xc,
                        float* __restrict__ dtp, float* __restrict__ Bm,
                        float* __restrict__ Cm) {
  constexpr int ROWS = DTR + 32;
  constexpr int NU = (ROWS + 3) / 4;
  __shared__ float sx[DI][68];
  const int tx = threadIdx.x;
  const int ty = threadIdx.y;
  const int tid = ty*64 + tx;
  const int t0 = blockIdx.x*64;
  for (int idx = tid; idx < DI*67; idx += 256){
    int d = idx / 67, j = idx - d*67;
    int t = t0 - 3 + j;
    sx[d][j] = (t >= 0) ? xs[d*L_TOT + t] : 0.f;
  }
  __syncthreads();
  float vals[DI/4];
#pragma unroll
  for (int k = 0; k < DI/4; k++){
    int r = ty + 4*k;
    float acc = cb[r] + cw[r*4+0]*sx[r][tx]   + cw[r*4+1]*sx[r][tx+1]
                      + cw[r*4+2]*sx[r][tx+2] + cw[r*4+3]*sx[r][tx+3];
    acc = acc * fsigmoid(acc);
    vals[k] = acc;
    xc[r*L_TOT + t0 + tx] = acc;
  }
  __syncthreads();
#pragma unroll
  for (int k = 0; k < DI/4; k++) sx[ty + 4*k][tx] = vals[k];
  __syncthreads();
  float a[NU];
#pragma unroll
  for (int u=0;u<NU;u++) a[u]=0.f;
  for (int d=0; d<DI; d++){
    float xv = sx[d][tx];
#pragma unroll
    for (int u=0;u<NU;u++){
      int r = ty + 4*u;
      if (r < ROWS) a[u] += xv * xpw[r*DI + d];
    }
  }
  const int t = t0 + tx;
#pragma unroll
  for (int u=0;u<NU;u++){
    int r = ty + 4*u;
    if (r < ROWS){
      if (r < DTR) dtp[r*L_TOT+t] = a[u];
      else if (r < DTR+16) Bm[(r-DTR)*L_TOT+t] = a[u];
      else Cm[(r-DTR-16)*L_TOT+t] = a[u];
    }
  }
}

// ---------------- scan pass 1 — per-chunk aggregates, s-states in registers -------
template<int DI, int SPB, int DTR, int LCH>
__global__ __launch_bounds__(128) void k_pass1(const float* __restrict__ dtp,
                        const float* __restrict__ xc,
                        const float* __restrict__ Bm, const float* __restrict__ Alog,
                        const float* __restrict__ dtw, const float* __restrict__ dtb,
                        float* __restrict__ aggA, float* __restrict__ aggB) {
  constexpr int NSH = 16/SPB;
  constexpr int CH = DI*16;
  __shared__ __align__(16) float sxc[DI][17], sdt[DI][17], sB[16][20];
  const int tid = threadIdx.x;
  const int d = tid / NSH, sh = tid - d*NSH;
  const int chunk = blockIdx.x;
  const int t0 = chunk*LCH;
  const int col = tid & 15, rw = tid >> 4;
  float Av[SPB], Ar[SPB], Br[SPB];
#pragma unroll
  for (int j=0;j<SPB;j++){
    Av[j] = -__expf(Alog[d*16 + sh*SPB + j]);
    Ar[j]=1.f; Br[j]=0.f;
  }
  for (int tb=0; tb<LCH; tb+=16){
    const int bt = t0 + tb;
#pragma unroll
    for (int rr2=0; rr2<DI/8; rr2++){
      int row = rw + rr2*8;
      sxc[row][col] = xc[row*L_TOT + bt + col];
      float pre = dtb[row] + dtw[row*DTR]*dtp[bt+col];
      if (DTR>1) pre += dtw[row*DTR+DTR-1]*dtp[(DTR-1)*L_TOT + bt + col];
      sdt[row][col] = fsoftplus(pre);
    }
#pragma unroll
    for (int ss=0; ss<2; ss++){
      int sidx = rw + ss*8;
      sB[col][sidx] = Bm[sidx*L_TOT + bt + col];
    }
    __syncthreads();
#pragma unroll
    for (int q=0;q<16;q++){
      float dtv = sdt[d][q];
      float bb  = dtv * sxc[d][q];
      float bx[SPB];
      {
        float4 b0 = *reinterpret_cast<const float4*>(&sB[q][sh*SPB]);
        bx[0]=b0.x; bx[1]=b0.y; bx[2]=b0.z; bx[3]=b0.w;
        if constexpr (SPB==8){
          float4 b1 = *reinterpret_cast<const float4*>(&sB[q][sh*SPB+4]);
          bx[4]=b1.x; bx[5]=b1.y; bx[6]=b1.z; bx[7]=b1.w;
        }
      }
#pragma unroll
      for (int j=0;j<SPB;j++){
        float a = __expf(dtv*Av[j]);
        Ar[j] *= a;
        Br[j] = a*Br[j] + bb*bx[j];
      }
    }
    __syncthreads();
  }
  int o = chunk*CH + d*16 + sh*SPB;
#pragma unroll
  for (int j=0;j<SPB;j++){ aggA[o+j]=Ar[j]; aggB[o+j]=Br[j]; }
}

// ---------------- parallel scan over chunk aggregates → carries -------------------
template<int NCH>
__global__ __launch_bounds__(1024) void k_carry(const float* __restrict__ aggA,
                        const float* __restrict__ aggB,
                        float* __restrict__ carry, int CH) {
  constexpr int SEG = NCH/16;
  int lane = threadIdx.x & 63;
  int seg  = threadIdx.x >> 6;
  int ch   = blockIdx.x*64 + lane;
  int c0   = seg*SEG;
  float a = 1.f, b = 0.f;
  for (int cb=c0; cb<c0+SEG; cb+=8){
    float av[8], bv[8];
#pragma unroll
    for (int k=0;k<8;k++){ av[k]=aggA[(cb+k)*CH+ch]; bv[k]=aggB[(cb+k)*CH+ch]; }
#pragma unroll
    for (int k=0;k<8;k++){ a = a*av[k]; b = av[k]*b + bv[k]; }
  }
  __shared__ float sa[16][64], sb[16][64];
  sa[seg][lane]=a; sb[seg][lane]=b;
  __syncthreads();
  if (seg==0){
    float pa=1.f, pb=0.f;
    for (int g=0; g<16; g++){
      float ca=sa[g][lane], cb2=sb[g][lane];
      sa[g][lane]=pa; sb[g][lane]=pb;
      float na = pa*ca;
      float nb = ca*pb + cb2;
      pa=na; pb=nb;
    }
  }
  __syncthreads();
  float h = sb[seg][lane];
  for (int cb=c0; cb<c0+SEG; cb+=8){
    float av[8], bv[8];
#pragma unroll
    for (int k=0;k<8;k++){ av[k]=aggA[(cb+k)*CH+ch]; bv[k]=aggB[(cb+k)*CH+ch]; }
#pragma unroll
    for (int k=0;k<8;k++){ carry[(cb+k)*CH+ch]=h; h = av[k]*h + bv[k]; }
  }
}

// ---------------- scan pass 2 — registers-per-(d,sgroup), y via LDS tile ----------
template<int DI, int SPB, int DTR, int LCH>
__global__ __launch_bounds__(128) void k_pass2(const float* __restrict__ dtp,
                        const float* __restrict__ xc,
                        const float* __restrict__ Bm, const float* __restrict__ Cm,
                        const float* __restrict__ z,  const float* __restrict__ Alog,
                        const float* __restrict__ dtw, const float* __restrict__ dtb,
                        const float* __restrict__ Dp, const float* __restrict__ carry,
                        float* __restrict__ yg) {
  constexpr int NSH = 16/SPB;
  constexpr int CH = DI*16;
  __shared__ __align__(16) float sxc[DI][17], sdt[DI][17], sz[DI][17], sy[DI][17];
  __shared__ __align__(16) float sB[16][20], sC[16][20];
  const int tid = threadIdx.x;
  const int d = tid / NSH, sh = tid - d*NSH;
  const int chunk = blockIdx.x;
  const int t0 = chunk*LCH;
  const int col = tid & 15, rw = tid >> 4;
  float Av[SPB], h[SPB];
#pragma unroll
  for (int j=0;j<SPB;j++){
    Av[j] = -__expf(Alog[d*16 + sh*SPB + j]);
    h[j]  = carry[chunk*CH + d*16 + sh*SPB + j];
  }
  const float Dv = Dp[d];
  for (int tb=0; tb<LCH; tb+=16){
    const int bt = t0 + tb;
#pragma unroll
    for (int rr2=0; rr2<DI/8; rr2++){
      int row = rw + rr2*8;
      sxc[row][col] = xc[row*L_TOT + bt + col];
      sz [row][col] = z [row*L_TOT + bt + col];
      float pre = dtb[row] + dtw[row*DTR]*dtp[bt+col];
      if (DTR>1) pre += dtw[row*DTR+DTR-1]*dtp[(DTR-1)*L_TOT + bt + col];
      sdt[row][col] = fsoftplus(pre);
    }
#pragma unroll
    for (int ss=0; ss<2; ss++){
      int sidx = rw + ss*8;
      sB[col][sidx] = Bm[sidx*L_TOT + bt + col];
      sC[col][sidx] = Cm[sidx*L_TOT + bt + col];
    }
    __syncthreads();
#pragma unroll
    for (int q=0;q<16;q++){
      float dtv = sdt[d][q];
      float xcv = sxc[d][q];
      float bb  = dtv * xcv;
      float bx[SPB], cx[SPB];
      {
        float4 b0 = *reinterpret_cast<const float4*>(&sB[q][sh*SPB]);
        float4 c0v = *reinterpret_cast<const float4*>(&sC[q][sh*SPB]);
        bx[0]=b0.x; bx[1]=b0.y; bx[2]=b0.z; bx[3]=b0.w;
        cx[0]=c0v.x; cx[1]=c0v.y; cx[2]=c0v.z; cx[3]=c0v.w;
        if constexpr (SPB==8){
          float4 b1 = *reinterpret_cast<const float4*>(&sB[q][sh*SPB+4]);
          float4 c1v = *reinterpret_cast<const float4*>(&sC[q][sh*SPB+4]);
          bx[4]=b1.x; bx[5]=b1.y; bx[6]=b1.z; bx[7]=b1.w;
          cx[4]=c1v.x; cx[5]=c1v.y; cx[6]=c1v.z; cx[7]=c1v.w;
        }
      }
      float p = 0.f;
#pragma unroll
      for (int j=0;j<SPB;j++){
        float a = __expf(dtv*Av[j]);
        h[j] = a*h[j] + bb*bx[j];
        p += h[j]*cx[j];
      }
#pragma unroll
      for (int o=1;o<NSH;o<<=1) p += __shfl_xor(p, o);
      if (sh==0){
        float zv = sz[d][q];
        sy[d][q] = (p + xcv*Dv) * (zv * fsigmoid(zv));
      }
    }
    __syncthreads();
#pragma unroll
    for (int rr2=0; rr2<DI/8; rr2++){
      int row = rw + rr2*8;
      yg[row*L_TOT + bt + col] = sy[row][col];
    }
  }
}

// ---------------- out-proj: thread = 4 rows, + residual → PADDED bf16 layout ------
template<int DIM, int DI, int RES>
__global__ __launch_bounds__(256) void k_outproj(const float* __restrict__ yg, const float* __restrict__ ow,
                          const float* __restrict__ r0src, const float* __restrict__ r1src,
                          const float* __restrict__ bstats, const float* __restrict__ bg,
                          const float* __restrict__ bb,
                          unsigned short* __restrict__ rp) {
  int t = blockIdx.x*64 + threadIdx.x;
  int i0 = (blockIdx.y*4 + threadIdx.y)*4;
  int zz = t / 2304;
  int r2 = t - zz*2304;
  int yy = r2 / 48;
  int xx = r2 - yy*48;
  int pb = (zz+1)*2500 + (yy+1)*50 + (xx+1);
  float a[4]={0.f,0.f,0.f,0.f};
  for (int d=0; d<DI; d++){
    float yv = yg[d*L_TOT+t];
#pragma unroll
    for (int u=0;u<4;u++) a[u] += yv*ow[(i0+u)*DI+d];
  }
#pragma unroll
  for (int u=0;u<4;u++){
    int i=i0+u;
    float res;
    if (RES==0){
      res = (i<16)? r0src[i*L_TOT+t] : r1src[(i-16)*L_TOT+t];
    } else {
      float bm = bstats[2*i]*(1.f/L_TOT);
      float bv = bstats[2*i+1]*(1.f/L_TOT) - bm*bm;
      res = (r0src[i*L_TOT+t]-bm)*rsqrtf(bv+BN_EPS)*bg[i] + bb[i];
    }
    rp[i*PCH+pb] = f2bf(a[u] + res);
  }
}

// ---------------- conv3d via MFMA implicit GEMM (bf16 in, fp32 accum) -------------
template<int IC>
__global__ __launch_bounds__(256) void k_conv_mfma(const unsigned short* __restrict__ bin,
                         const unsigned short* __restrict__ wA,
                         const float* __restrict__ bias, float* __restrict__ out) {
  constexpr int NKB = (IC==32) ? 27 : 14;
  const int lane = threadIdx.x & 63;
  const int n = lane & 15, quad = lane >> 4;
  const int tile = blockIdx.x*4 + (threadIdx.x >> 6);
  const int t = tile*16 + n;
  int zz = t / 2304;
  int r2 = t - zz*2304;
  int yy = r2 / 48;
  int xx = r2 - yy*48;
  int pb = (zz+1)*2500 + (yy+1)*50 + (xx+1);
  const unsigned short* bp[8];
#pragma unroll
  for (int j=0;j<8;j++){
    int e = quad*8 + j;
    int ic = (IC==32) ? e : (e & 15);
    bp[j] = bin + ic*PCH + pb;
  }
  const int rq = (IC==32) ? 0 : (quad >> 1);
  f32x4 acc = {0.f, 0.f, 0.f, 0.f};
#pragma unroll
  for (int kb=0; kb<NKB; kb++){
    bf16x8 af = *reinterpret_cast<const bf16x8*>(wA + (size_t)((kb*4+quad)*16 + n)*8);
    int off;
    if (IC==32) off = off3c(kb);
    else        off = rq ? off3c(2*kb+1) : off3c(2*kb);
    bf16x8 bf;
#pragma unroll
    for (int j=0;j<8;j++) bf[j] = (short)bp[j][off];
    acc = __builtin_amdgcn_mfma_f32_16x16x32_bf16(af, bf, acc, 0, 0, 0);
  }
#pragma unroll
  for (int reg=0; reg<4; reg++){
    int m = quad*4 + reg;
    out[m*L_TOT + t] = acc[reg] + bias[m];
  }
}

// ---------------- BN reduce: segment-split + atomic -------------------------------
__global__ void k_bn_reduce(const float* __restrict__ x, float* __restrict__ stats) {
  int c = blockIdx.x; int seg = blockIdx.y; int tid = threadIdx.x;
  const int SL = L_TOT/8;
  int base = c*L_TOT + seg*SL;
  float s=0.f, s2=0.f;
  for (int i=tid;i<SL;i+=256){ float v = x[base+i]; s+=v; s2+=v*v; }
  for (int o=1;o<64;o<<=1){ s += __shfl_xor(s,o); s2 += __shfl_xor(s2,o); }
  __shared__ float ls[4], ls2[4];
  int wv = tid>>6;
  if ((tid&63)==0){ ls[wv]=s; ls2[wv]=s2; }
  __syncthreads();
  if (tid==0){
    atomicAdd(&stats[2*c],   ls[0]+ls[1]+ls[2]+ls[3]);
    atomicAdd(&stats[2*c+1], ls2[0]+ls2[1]+ls2[2]+ls2[3]);
  }
}

// ---------------- BN normalize, float4 --------------------------------------------
__global__ void k_bn_norm4(const float* __restrict__ raw, const float* __restrict__ stats,
                           const float* __restrict__ g, const float* __restrict__ b,
                           float* __restrict__ out) {
  int i = blockIdx.x*256 + threadIdx.x;         // over 16*L_TOT/4
  int c = i / (L_TOT/4);
  int tq = i - c*(L_TOT/4);
  float m = stats[2*c]*(1.f/L_TOT);
  float v = stats[2*c+1]*(1.f/L_TOT) - m*m;
  float sc = rsqrtf(v+BN_EPS)*g[c];
  float bs = b[c] - m*sc;
  float4 x = *reinterpret_cast<const float4*>(raw + c*L_TOT + tq*4);
  float4 o = make_float4(x.x*sc+bs, x.y*sc+bs, x.z*sc+bs, x.w*sc+bs);
  *reinterpret_cast<float4*>(out + c*L_TOT + tq*4) = o;
}

// =================================================================================
extern "C" void kernel_launch(void* const* d_in, const int* in_sizes, int n_in,
                              void* d_out, int out_size, void* d_ws, size_t ws_size,
                              hipStream_t stream) {
  const float* l        = (const float*)d_in[0];
  const float* s        = (const float*)d_in[1];
  const float* m1_ln_w  = (const float*)d_in[2];
  const float* m1_ln_b  = (const float*)d_in[3];
  const float* m1_in_w  = (const float*)d_in[4];
  const float* m1_cw    = (const float*)d_in[5];
  const float* m1_cb    = (const float*)d_in[6];
  const float* m1_xp_w  = (const float*)d_in[7];
  const float* m1_dt_w  = (const float*)d_in[8];
  const float* m1_dt_b  = (const float*)d_in[9];
  const float* m1_Alog  = (const float*)d_in[10];
  const float* m1_D     = (const float*)d_in[11];
  const float* m1_out_w = (const float*)d_in[12];
  const float* m2_ln_w  = (const float*)d_in[13];
  const float* m2_ln_b  = (const float*)d_in[14];
  const float* m2_in_w  = (const float*)d_in[15];
  const float* m2_cw    = (const float*)d_in[16];
  const float* m2_cb    = (const float*)d_in[17];
  const float* m2_xp_w  = (const float*)d_in[18];
  const float* m2_dt_w  = (const float*)d_in[19];
  const float* m2_dt_b  = (const float*)d_in[20];
  const float* m2_Alog  = (const float*)d_in[21];
  const float* m2_D     = (const float*)d_in[22];
  const float* m2_out_w = (const float*)d_in[23];
  const float* c1_w     = (const float*)d_in[24];
  const float* c1_b     = (const float*)d_in[25];
  const float* bn1_g    = (const float*)d_in[26];
  const float* bn1_b    = (const float*)d_in[27];
  const float* c2_w     = (const float*)d_in[28];
  const float* c2_b     = (const float*)d_in[29];
  const float* bn2_g    = (const float*)d_in[30];
  const float* bn2_b    = (const float*)d_in[31];

  float* ws = (float*)d_ws;
  const size_t L = L_TOT;
  float* xs1      = ws;              // 0..64    dead after dwxp1
  float* yg1      = ws;              // alias    written by pass2_1, read by outproj1
  float* conv1raw = ws;              // alias 0..16  written by conv1; lives thru stage2
  float* z1       = ws + 64*L;       // 64..128  dead after pass2_1
  unsigned short* bfin = (unsigned short*)(ws + 64*L);  // alias over dead z1: 32*PCH ushorts
  float* xc1      = ws + 128*L;      // 128..192 dead after pass2_1
  float* xs2      = ws + 128*L;      // alias 128..160
  float* z2       = ws + 160*L;      // 160..192
  float* dtp      = ws + 192*L;      // 192..194 (shared stage1/2)
  float* B1       = ws + 194*L;      // 194..210 (shared)
  float* C1       = ws + 210*L;      // 210..226 (shared)
  float* xc2      = ws + 226*L;      // 226..258
  float* yg2      = ws + 258*L;      // 258..290
  float* conv2raw = ws + 290*L;      // 290..306
  float* stats1   = ws + 306*L;      // 32 floats
  float* stats2   = stats1 + 32;     // 32 floats
  float* aggA     = ws + 320*L;      // 786432 = 21.33L
  float* aggB     = aggA + 786432;
  float* carry    = aggB + 786432;   // ends exactly at 384L
  unsigned short* wA1 = (unsigned short*)(ws + 384*L);
  unsigned short* wA2 = (unsigned short*)(ws + 384*L) + 14336;

  k_setup<<<6,256,0,stream>>>(c1_w, wA1, c2_w, wA2, stats1);

  // ================= stage 1: mamba(dim=32, di=64) + conv1 + bn1(stats) ==========
  k_inproj<32,64,false,8><<<dim3(576,4),dim3(64,4),0,stream>>>(l, s, stats1, bn1_g, bn1_b,
                                                               m1_ln_w, m1_ln_b, m1_in_w, xs1, z1);
  k_dwxp<64,2><<<576,dim3(64,4),0,stream>>>(xs1, m1_cw, m1_cb, m1_xp_w, xc1, dtp, B1, C1);
  k_pass1<64,8,2,LCH1><<<NCH1,128,0,stream>>>(dtp, xc1, B1, m1_Alog, m1_dt_w, m1_dt_b, aggA, aggB);
  k_carry<NCH1><<<16,1024,0,stream>>>(aggA, aggB, carry, 1024);
  k_pass2<64,8,2,LCH1><<<NCH1,128,0,stream>>>(dtp, xc1, B1, C1, z1, m1_Alog, m1_dt_w, m1_dt_b, m1_D, carry, yg1);
  // z1 dead -> zero bf16 conv-input region (halo covers both stages)
  k_zero<<<(16*PCH+255)/256,256,0,stream>>>((float*)bfin, 16*PCH);
  k_outproj<32,64,0><<<dim3(576,2),dim3(64,4),0,stream>>>(yg1, m1_out_w, l, s,
                                                          stats1, bn1_g, bn1_b, bfin);
  k_conv_mfma<32><<<576,256,0,stream>>>(bfin, wA1, c1_b, conv1raw);
  k_bn_reduce<<<dim3(16,8),256,0,stream>>>(conv1raw, stats1);

  // ================= stage 2: mamba(dim=16, di=32) + conv2 + bn2 =================
  k_inproj<16,32,true,8><<<dim3(576,2),dim3(64,4),0,stream>>>(conv1raw, conv1raw, stats1, bn1_g, bn1_b,
                                                              m2_ln_w, m2_ln_b, m2_in_w, xs2, z2);
  k_dwxp<32,1><<<576,dim3(64,4),0,stream>>>(xs2, m2_cw, m2_cb, m2_xp_w, xc2, dtp, B1, C1);
  k_pass1<32,4,1,LCH2><<<NCH2,128,0,stream>>>(dtp, xc2, B1, m2_Alog, m2_dt_w, m2_dt_b, aggA, aggB);
  k_carry<NCH2><<<8,1024,0,stream>>>(aggA, aggB, carry, 512);
  k_pass2<32,4,1,LCH2><<<NCH2,128,0,stream>>>(dtp, xc2, B1, C1, z2, m2_Alog, m2_dt_w, m2_dt_b, m2_D, carry, yg2);
  k_outproj<16,32,1><<<dim3(576,1),dim3(64,4),0,stream>>>(yg2, m2_out_w, conv1raw, conv1raw,
                                                          stats1, bn1_g, bn1_b, bfin);
  k_conv_mfma<16><<<576,256,0,stream>>>(bfin, wA2, c2_b, conv2raw);
  k_bn_reduce<<<dim3(16,8),256,0,stream>>>(conv2raw, stats2);
  k_bn_norm4<<<576,256,0,stream>>>(conv2raw, stats2, bn2_g, bn2_b, (float*)d_out);
}

// Round 18
// 340.020 us; speedup vs baseline: 1.1198x; 1.1198x over previous
//
#include <hip/hip_runtime.h>
#include <math.h>

#define L_TOT 36864
#define BN_EPS 1e-5f
#define PCH 45000   // padded channel stride: 18*50*50

#define NCH1 768
#define LCH1 48
#define NCH2 1152
#define LCH2 32

typedef __attribute__((ext_vector_type(8))) short bf16x8;
typedef __attribute__((ext_vector_type(4))) float f32x4;

__device__ __forceinline__ float fsigmoid(float x){ return 1.f/(1.f+__expf(-x)); }
__device__ __forceinline__ float fsoftplus(float x){
  float e = __expf(x);
  return (x>20.f)? x : __logf(1.f+e);
}
__device__ __forceinline__ unsigned short f2bf(float x){
  union { float f; unsigned u; } cv; cv.f = x;
  unsigned r = (cv.u + 0x7FFFu + ((cv.u>>16)&1u)) >> 16;
  return (unsigned short)r;
}
__host__ __device__ constexpr int off3c(int r){
  return (r>=27) ? 0 : ((r/9)-1)*2500 + (((r%9)/3)-1)*50 + ((r%3)-1);
}

// ---------------- zero-fill (32-bit words) ----------------------------------------
__global__ void k_zero(float* __restrict__ p, int n) {
  int i = blockIdx.x*256 + threadIdx.x;
  if (i < n) p[i] = 0.f;
}

// ---------------- setup: pack both conv weights (bf16 A-fragments) + zero stats ---
__global__ void k_setup(const float* __restrict__ w1, unsigned short* __restrict__ wA1,
                        const float* __restrict__ w2, unsigned short* __restrict__ wA2,
                        float* __restrict__ stats) {
  int b = blockIdx.x, tid = threadIdx.x;
  if (b < 4){
    int k = b*256 + tid;
    if (k < 864){
      int ic = k & 31, r = k >> 5;
      for (int m=0;m<16;m++){
        float v = (r < 27) ? w1[m*32*27 + ic*27 + r] : 0.f;
        wA1[(((k>>3)*16) + m)*8 + (k&7)] = f2bf(v);
      }
    }
  } else {
    int k = (b-4)*256 + tid;
    if (k < 448){
      int ic = k & 15, r = k >> 4;
      for (int m=0;m<16;m++){
        float v = (r < 27) ? w2[m*16*27 + ic*27 + r] : 0.f;
        wA2[(((k>>3)*16) + m)*8 + (k&7)] = f2bf(v);
      }
    }
    if (b==5 && tid>=192) stats[tid-192] = 0.f;
  }
}

// ---------------- in-proj with fused LayerNorm, NU rows per thread ----------------
template<int DIM, int DI, bool DOBN, int NU>
__global__ __launch_bounds__(256) void k_inproj(const float* __restrict__ x0, const float* __restrict__ x1,
                         const float* __restrict__ bstats, const float* __restrict__ bg,
                         const float* __restrict__ bb,
                         const float* __restrict__ lnw, const float* __restrict__ lnb,
                         const float* __restrict__ inw,
                         float* __restrict__ xs, float* __restrict__ z) {
  int t = blockIdx.x*64 + threadIdx.x;
  int j0 = (blockIdx.y*4 + threadIdx.y)*NU;
  float xv[DIM];
  float s=0.f, s2=0.f;
#pragma unroll
  for (int c=0;c<DIM;c++){
    float v = (c<16)? x0[c*L_TOT+t] : x1[(c-16)*L_TOT+t];
    if (DOBN){
      float bm = bstats[2*c]*(1.f/L_TOT);
      float bv = bstats[2*c+1]*(1.f/L_TOT) - bm*bm;
      v = (v-bm)*rsqrtf(bv+BN_EPS)*bg[c] + bb[c];
    }
    xv[c]=v; s += v; s2 += v*v;
  }
  float m = s*(1.f/DIM);
  float var = s2*(1.f/DIM) - m*m;
  float rs = rsqrtf(var + BN_EPS);
  float a[NU];
#pragma unroll
  for (int u=0;u<NU;u++) a[u]=0.f;
#pragma unroll
  for (int c=0;c<DIM;c++){
    float xn = (xv[c]-m)*rs*lnw[c] + lnb[c];
#pragma unroll
    for (int u=0;u<NU;u++) a[u] += xn*inw[(j0+u)*DIM+c];
  }
#pragma unroll
  for (int u=0;u<NU;u++){
    int j=j0+u;
    if (j<DI) xs[j*L_TOT+t]=a[u]; else z[(j-DI)*L_TOT+t]=a[u];
  }
}

// ---------------- causal depthwise conv (kw=4) + SiLU, float4 vectorized ----------
template<int DI>
__global__ void k_dwconv(const float* __restrict__ xs, const float* __restrict__ cw,
                         const float* __restrict__ cb, float* __restrict__ xc) {
  int i = blockIdx.x*256 + threadIdx.x;          // i over DI*L_TOT/4
  int d = i / (L_TOT/4);
  int tq = i - d*(L_TOT/4);
  int t0 = tq*4;
  const float* row = xs + d*L_TOT;
  float4 cur = *reinterpret_cast<const float4*>(row + t0);
  float4 prev = (tq>0) ? *reinterpret_cast<const float4*>(row + t0 - 4)
                       : make_float4(0.f,0.f,0.f,0.f);
  float w8[8] = {prev.x,prev.y,prev.z,prev.w,cur.x,cur.y,cur.z,cur.w};
  float c0=cw[d*4+0], c1=cw[d*4+1], c2=cw[d*4+2], c3=cw[d*4+3];
  float bias=cb[d];
  float4 o;
#pragma unroll
  for (int j=0;j<4;j++){
    float acc = bias + c0*w8[j+1] + c1*w8[j+2] + c2*w8[j+3] + c3*w8[j+4];
    ((float*)&o)[j] = acc * fsigmoid(acc);
  }
  *reinterpret_cast<float4*>(xc + d*L_TOT + t0) = o;
}

// ---------------- x-proj: thread = 4 rows of (dtp|B|C), streamed K ----------------
template<int DI, int DTR>
__global__ __launch_bounds__(256) void k_xproj(const float* __restrict__ xc, const float* __restrict__ xpw,
                        float* __restrict__ dtp, float* __restrict__ Bm, float* __restrict__ Cm) {
  constexpr int ROWS = DTR + 32;
  int t = blockIdx.x*64 + threadIdx.x;
  int r0 = (blockIdx.y*4 + threadIdx.y)*4;
  int rr[4];
#pragma unroll
  for (int u=0;u<4;u++) rr[u] = (r0+u<ROWS)? r0+u : 0;
  float a[4]={0.f,0.f,0.f,0.f};
  for (int d=0; d<DI; d++){
    float xv = xc[d*L_TOT+t];
#pragma unroll
    for (int u=0;u<4;u++) a[u] += xv*xpw[rr[u]*DI+d];
  }
#pragma unroll
  for (int u=0;u<4;u++){
    int r=r0+u;
    if (r<DTR) dtp[r*L_TOT+t]=a[u];
    else if (r<DTR+16) Bm[(r-DTR)*L_TOT+t]=a[u];
    else if (r<ROWS)   Cm[(r-DTR-16)*L_TOT+t]=a[u];
  }
}

// ---------------- scan pass 1 — per-chunk aggregates, s-states in registers -------
template<int DI, int SPB, int DTR, int LCH>
__global__ __launch_bounds__(128) void k_pass1(const float* __restrict__ dtp,
                        const float* __restrict__ xc,
                        const float* __restrict__ Bm, const float* __restrict__ Alog,
                        const float* __restrict__ dtw, const float* __restrict__ dtb,
                        float* __restrict__ aggA, float* __restrict__ aggB) {
  constexpr int NSH = 16/SPB;
  constexpr int CH = DI*16;
  __shared__ __align__(16) float sxc[DI][17], sdt[DI][17], sB[16][20];
  const int tid = threadIdx.x;
  const int d = tid / NSH, sh = tid - d*NSH;
  const int chunk = blockIdx.x;
  const int t0 = chunk*LCH;
  const int col = tid & 15, rw = tid >> 4;
  float Av[SPB], Ar[SPB], Br[SPB];
#pragma unroll
  for (int j=0;j<SPB;j++){
    Av[j] = -__expf(Alog[d*16 + sh*SPB + j]);
    Ar[j]=1.f; Br[j]=0.f;
  }
  for (int tb=0; tb<LCH; tb+=16){
    const int bt = t0 + tb;
#pragma unroll
    for (int rr2=0; rr2<DI/8; rr2++){
      int row = rw + rr2*8;
      sxc[row][col] = xc[row*L_TOT + bt + col];
      float pre = dtb[row] + dtw[row*DTR]*dtp[bt+col];
      if (DTR>1) pre += dtw[row*DTR+DTR-1]*dtp[(DTR-1)*L_TOT + bt + col];
      sdt[row][col] = fsoftplus(pre);
    }
#pragma unroll
    for (int ss=0; ss<2; ss++){
      int sidx = rw + ss*8;
      sB[col][sidx] = Bm[sidx*L_TOT + bt + col];
    }
    __syncthreads();
#pragma unroll
    for (int q=0;q<16;q++){
      float dtv = sdt[d][q];
      float bb  = dtv * sxc[d][q];
      float bx[SPB];
      {
        float4 b0 = *reinterpret_cast<const float4*>(&sB[q][sh*SPB]);
        bx[0]=b0.x; bx[1]=b0.y; bx[2]=b0.z; bx[3]=b0.w;
        if constexpr (SPB==8){
          float4 b1 = *reinterpret_cast<const float4*>(&sB[q][sh*SPB+4]);
          bx[4]=b1.x; bx[5]=b1.y; bx[6]=b1.z; bx[7]=b1.w;
        }
      }
#pragma unroll
      for (int j=0;j<SPB;j++){
        float a = __expf(dtv*Av[j]);
        Ar[j] *= a;
        Br[j] = a*Br[j] + bb*bx[j];
      }
    }
    __syncthreads();
  }
  int o = chunk*CH + d*16 + sh*SPB;
#pragma unroll
  for (int j=0;j<SPB;j++){ aggA[o+j]=Ar[j]; aggB[o+j]=Br[j]; }
}

// ---------------- parallel scan over chunk aggregates → carries -------------------
template<int NCH>
__global__ __launch_bounds__(1024) void k_carry(const float* __restrict__ aggA,
                        const float* __restrict__ aggB,
                        float* __restrict__ carry, int CH) {
  constexpr int SEG = NCH/16;
  int lane = threadIdx.x & 63;
  int seg  = threadIdx.x >> 6;
  int ch   = blockIdx.x*64 + lane;
  int c0   = seg*SEG;
  float a = 1.f, b = 0.f;
  for (int cb=c0; cb<c0+SEG; cb+=8){
    float av[8], bv[8];
#pragma unroll
    for (int k=0;k<8;k++){ av[k]=aggA[(cb+k)*CH+ch]; bv[k]=aggB[(cb+k)*CH+ch]; }
#pragma unroll
    for (int k=0;k<8;k++){ a = a*av[k]; b = av[k]*b + bv[k]; }
  }
  __shared__ float sa[16][64], sb[16][64];
  sa[seg][lane]=a; sb[seg][lane]=b;
  __syncthreads();
  if (seg==0){
    float pa=1.f, pb=0.f;
    for (int g=0; g<16; g++){
      float ca=sa[g][lane], cb2=sb[g][lane];
      sa[g][lane]=pa; sb[g][lane]=pb;
      float na = pa*ca;
      float nb = ca*pb + cb2;
      pa=na; pb=nb;
    }
  }
  __syncthreads();
  float h = sb[seg][lane];
  for (int cb=c0; cb<c0+SEG; cb+=8){
    float av[8], bv[8];
#pragma unroll
    for (int k=0;k<8;k++){ av[k]=aggA[(cb+k)*CH+ch]; bv[k]=aggB[(cb+k)*CH+ch]; }
#pragma unroll
    for (int k=0;k<8;k++){ carry[(cb+k)*CH+ch]=h; h = av[k]*h + bv[k]; }
  }
}

// ---------------- scan pass 2 — registers-per-(d,sgroup), y via LDS tile ----------
template<int DI, int SPB, int DTR, int LCH>
__global__ __launch_bounds__(128) void k_pass2(const float* __restrict__ dtp,
                        const float* __restrict__ xc,
                        const float* __restrict__ Bm, const float* __restrict__ Cm,
                        const float* __restrict__ z,  const float* __restrict__ Alog,
                        const float* __restrict__ dtw, const float* __restrict__ dtb,
                        const float* __restrict__ Dp, const float* __restrict__ carry,
                        float* __restrict__ yg) {
  constexpr int NSH = 16/SPB;
  constexpr int CH = DI*16;
  __shared__ __align__(16) float sxc[DI][17], sdt[DI][17], sz[DI][17], sy[DI][17];
  __shared__ __align__(16) float sB[16][20], sC[16][20];
  const int tid = threadIdx.x;
  const int d = tid / NSH, sh = tid - d*NSH;
  const int chunk = blockIdx.x;
  const int t0 = chunk*LCH;
  const int col = tid & 15, rw = tid >> 4;
  float Av[SPB], h[SPB];
#pragma unroll
  for (int j=0;j<SPB;j++){
    Av[j] = -__expf(Alog[d*16 + sh*SPB + j]);
    h[j]  = carry[chunk*CH + d*16 + sh*SPB + j];
  }
  const float Dv = Dp[d];
  for (int tb=0; tb<LCH; tb+=16){
    const int bt = t0 + tb;
#pragma unroll
    for (int rr2=0; rr2<DI/8; rr2++){
      int row = rw + rr2*8;
      sxc[row][col] = xc[row*L_TOT + bt + col];
      sz [row][col] = z [row*L_TOT + bt + col];
      float pre = dtb[row] + dtw[row*DTR]*dtp[bt+col];
      if (DTR>1) pre += dtw[row*DTR+DTR-1]*dtp[(DTR-1)*L_TOT + bt + col];
      sdt[row][col] = fsoftplus(pre);
    }
#pragma unroll
    for (int ss=0; ss<2; ss++){
      int sidx = rw + ss*8;
      sB[col][sidx] = Bm[sidx*L_TOT + bt + col];
      sC[col][sidx] = Cm[sidx*L_TOT + bt + col];
    }
    __syncthreads();
#pragma unroll
    for (int q=0;q<16;q++){
      float dtv = sdt[d][q];
      float xcv = sxc[d][q];
      float bb  = dtv * xcv;
      float bx[SPB], cx[SPB];
      {
        float4 b0 = *reinterpret_cast<const float4*>(&sB[q][sh*SPB]);
        float4 c0v = *reinterpret_cast<const float4*>(&sC[q][sh*SPB]);
        bx[0]=b0.x; bx[1]=b0.y; bx[2]=b0.z; bx[3]=b0.w;
        cx[0]=c0v.x; cx[1]=c0v.y; cx[2]=c0v.z; cx[3]=c0v.w;
        if constexpr (SPB==8){
          float4 b1 = *reinterpret_cast<const float4*>(&sB[q][sh*SPB+4]);
          float4 c1v = *reinterpret_cast<const float4*>(&sC[q][sh*SPB+4]);
          bx[4]=b1.x; bx[5]=b1.y; bx[6]=b1.z; bx[7]=b1.w;
          cx[4]=c1v.x; cx[5]=c1v.y; cx[6]=c1v.z; cx[7]=c1v.w;
        }
      }
      float p = 0.f;
#pragma unroll
      for (int j=0;j<SPB;j++){
        float a = __expf(dtv*Av[j]);
        h[j] = a*h[j] + bb*bx[j];
        p += h[j]*cx[j];
      }
#pragma unroll
      for (int o=1;o<NSH;o<<=1) p += __shfl_xor(p, o);
      if (sh==0){
        float zv = sz[d][q];
        sy[d][q] = (p + xcv*Dv) * (zv * fsigmoid(zv));
      }
    }
    __syncthreads();
#pragma unroll
    for (int rr2=0; rr2<DI/8; rr2++){
      int row = rw + rr2*8;
      yg[row*L_TOT + bt + col] = sy[row][col];
    }
  }
}

// ---------------- out-proj: thread = 4 rows, + residual → PADDED bf16 layout ------
template<int DIM, int DI, int RES>
__global__ __launch_bounds__(256) void k_outproj(const float* __restrict__ yg, const float* __restrict__ ow,
                          const float* __restrict__ r0src, const float* __restrict__ r1src,
                          const float* __restrict__ bstats, const float* __restrict__ bg,
                          const float* __restrict__ bb,
                          unsigned short* __restrict__ rp) {
  int t = blockIdx.x*64 + threadIdx.x;
  int i0 = (blockIdx.y*4 + threadIdx.y)*4;
  int zz = t / 2304;
  int r2 = t - zz*2304;
  int yy = r2 / 48;
  int xx = r2 - yy*48;
  int pb = (zz+1)*2500 + (yy+1)*50 + (xx+1);
  float a[4]={0.f,0.f,0.f,0.f};
  for (int d=0; d<DI; d++){
    float yv = yg[d*L_TOT+t];
#pragma unroll
    for (int u=0;u<4;u++) a[u] += yv*ow[(i0+u)*DI+d];
  }
#pragma unroll
  for (int u=0;u<4;u++){
    int i=i0+u;
    float res;
    if (RES==0){
      res = (i<16)? r0src[i*L_TOT+t] : r1src[(i-16)*L_TOT+t];
    } else {
      float bm = bstats[2*i]*(1.f/L_TOT);
      float bv = bstats[2*i+1]*(1.f/L_TOT) - bm*bm;
      res = (r0src[i*L_TOT+t]-bm)*rsqrtf(bv+BN_EPS)*bg[i] + bb[i];
    }
    rp[i*PCH+pb] = f2bf(a[u] + res);
  }
}

// ---------------- conv3d via MFMA implicit GEMM (bf16 in, fp32 accum) -------------
template<int IC>
__global__ __launch_bounds__(256) void k_conv_mfma(const unsigned short* __restrict__ bin,
                         const unsigned short* __restrict__ wA,
                         const float* __restrict__ bias, float* __restrict__ out) {
  constexpr int NKB = (IC==32) ? 27 : 14;
  const int lane = threadIdx.x & 63;
  const int n = lane & 15, quad = lane >> 4;
  const int tile = blockIdx.x*4 + (threadIdx.x >> 6);
  const int t = tile*16 + n;
  int zz = t / 2304;
  int r2 = t - zz*2304;
  int yy = r2 / 48;
  int xx = r2 - yy*48;
  int pb = (zz+1)*2500 + (yy+1)*50 + (xx+1);
  const unsigned short* bp[8];
#pragma unroll
  for (int j=0;j<8;j++){
    int e = quad*8 + j;
    int ic = (IC==32) ? e : (e & 15);
    bp[j] = bin + ic*PCH + pb;
  }
  const int rq = (IC==32) ? 0 : (quad >> 1);
  f32x4 acc = {0.f, 0.f, 0.f, 0.f};
#pragma unroll
  for (int kb=0; kb<NKB; kb++){
    bf16x8 af = *reinterpret_cast<const bf16x8*>(wA + (size_t)((kb*4+quad)*16 + n)*8);
    int off;
    if (IC==32) off = off3c(kb);
    else        off = rq ? off3c(2*kb+1) : off3c(2*kb);
    bf16x8 bf;
#pragma unroll
    for (int j=0;j<8;j++) bf[j] = (short)bp[j][off];
    acc = __builtin_amdgcn_mfma_f32_16x16x32_bf16(af, bf, acc, 0, 0, 0);
  }
#pragma unroll
  for (int reg=0; reg<4; reg++){
    int m = quad*4 + reg;
    out[m*L_TOT + t] = acc[reg] + bias[m];
  }
}

// ---------------- BN reduce: segment-split + atomic -------------------------------
__global__ void k_bn_reduce(const float* __restrict__ x, float* __restrict__ stats) {
  int c = blockIdx.x; int seg = blockIdx.y; int tid = threadIdx.x;
  const int SL = L_TOT/8;
  int base = c*L_TOT + seg*SL;
  float s=0.f, s2=0.f;
  for (int i=tid;i<SL;i+=256){ float v = x[base+i]; s+=v; s2+=v*v; }
  for (int o=1;o<64;o<<=1){ s += __shfl_xor(s,o); s2 += __shfl_xor(s2,o); }
  __shared__ float ls[4], ls2[4];
  int wv = tid>>6;
  if ((tid&63)==0){ ls[wv]=s; ls2[wv]=s2; }
  __syncthreads();
  if (tid==0){
    atomicAdd(&stats[2*c],   ls[0]+ls[1]+ls[2]+ls[3]);
    atomicAdd(&stats[2*c+1], ls2[0]+ls2[1]+ls2[2]+ls2[3]);
  }
}

// ---------------- BN normalize, float4 --------------------------------------------
__global__ void k_bn_norm4(const float* __restrict__ raw, const float* __restrict__ stats,
                           const float* __restrict__ g, const float* __restrict__ b,
                           float* __restrict__ out) {
  int i = blockIdx.x*256 + threadIdx.x;         // over 16*L_TOT/4
  int c = i / (L_TOT/4);
  int tq = i - c*(L_TOT/4);
  float m = stats[2*c]*(1.f/L_TOT);
  float v = stats[2*c+1]*(1.f/L_TOT) - m*m;
  float sc = rsqrtf(v+BN_EPS)*g[c];
  float bs = b[c] - m*sc;
  float4 x = *reinterpret_cast<const float4*>(raw + c*L_TOT + tq*4);
  float4 o = make_float4(x.x*sc+bs, x.y*sc+bs, x.z*sc+bs, x.w*sc+bs);
  *reinterpret_cast<float4*>(out + c*L_TOT + tq*4) = o;
}

// =================================================================================
extern "C" void kernel_launch(void* const* d_in, const int* in_sizes, int n_in,
                              void* d_out, int out_size, void* d_ws, size_t ws_size,
                              hipStream_t stream) {
  const float* l        = (const float*)d_in[0];
  const float* s        = (const float*)d_in[1];
  const float* m1_ln_w  = (const float*)d_in[2];
  const float* m1_ln_b  = (const float*)d_in[3];
  const float* m1_in_w  = (const float*)d_in[4];
  const float* m1_cw    = (const float*)d_in[5];
  const float* m1_cb    = (const float*)d_in[6];
  const float* m1_xp_w  = (const float*)d_in[7];
  const float* m1_dt_w  = (const float*)d_in[8];
  const float* m1_dt_b  = (const float*)d_in[9];
  const float* m1_Alog  = (const float*)d_in[10];
  const float* m1_D     = (const float*)d_in[11];
  const float* m1_out_w = (const float*)d_in[12];
  const float* m2_ln_w  = (const float*)d_in[13];
  const float* m2_ln_b  = (const float*)d_in[14];
  const float* m2_in_w  = (const float*)d_in[15];
  const float* m2_cw    = (const float*)d_in[16];
  const float* m2_cb    = (const float*)d_in[17];
  const float* m2_xp_w  = (const float*)d_in[18];
  const float* m2_dt_w  = (const float*)d_in[19];
  const float* m2_dt_b  = (const float*)d_in[20];
  const float* m2_Alog  = (const float*)d_in[21];
  const float* m2_D     = (const float*)d_in[22];
  const float* m2_out_w = (const float*)d_in[23];
  const float* c1_w     = (const float*)d_in[24];
  const float* c1_b     = (const float*)d_in[25];
  const float* bn1_g    = (const float*)d_in[26];
  const float* bn1_b    = (const float*)d_in[27];
  const float* c2_w     = (const float*)d_in[28];
  const float* c2_b     = (const float*)d_in[29];
  const float* bn2_g    = (const float*)d_in[30];
  const float* bn2_b    = (const float*)d_in[31];

  float* ws = (float*)d_ws;
  const size_t L = L_TOT;
  float* xs1      = ws;              // 0..64    dead after dwconv1
  float* yg1      = ws;              // alias    written by pass2_1, read by outproj1
  float* conv1raw = ws;              // alias 0..16  written by conv1; lives thru stage2
  float* z1       = ws + 64*L;       // 64..128  dead after pass2_1
  unsigned short* bfin = (unsigned short*)(ws + 64*L);  // alias over dead z1: 32*PCH ushorts
  float* xc1      = ws + 128*L;      // 128..192 dead after pass2_1
  float* xs2      = ws + 128*L;      // alias 128..160
  float* z2       = ws + 160*L;      // 160..192
  float* dtp      = ws + 192*L;      // 192..194 (shared stage1/2)
  float* B1       = ws + 194*L;      // 194..210 (shared)
  float* C1       = ws + 210*L;      // 210..226 (shared)
  float* xc2      = ws + 226*L;      // 226..258
  float* yg2      = ws + 258*L;      // 258..290
  float* conv2raw = ws + 290*L;      // 290..306
  float* stats1   = ws + 306*L;      // 32 floats
  float* stats2   = stats1 + 32;     // 32 floats
  float* aggA     = ws + 320*L;      // 786432 = 21.33L
  float* aggB     = aggA + 786432;
  float* carry    = aggB + 786432;   // ends exactly at 384L
  unsigned short* wA1 = (unsigned short*)(ws + 384*L);
  unsigned short* wA2 = (unsigned short*)(ws + 384*L) + 14336;

  k_setup<<<6,256,0,stream>>>(c1_w, wA1, c2_w, wA2, stats1);

  // ================= stage 1: mamba(dim=32, di=64) + conv1 + bn1(stats) ==========
  k_inproj<32,64,false,8><<<dim3(576,4),dim3(64,4),0,stream>>>(l, s, stats1, bn1_g, bn1_b,
                                                               m1_ln_w, m1_ln_b, m1_in_w, xs1, z1);
  k_dwconv<64><<<2304,256,0,stream>>>(xs1, m1_cw, m1_cb, xc1);
  k_xproj<64,2><<<dim3(576,3),dim3(64,4),0,stream>>>(xc1, m1_xp_w, dtp, B1, C1);
  k_pass1<64,8,2,LCH1><<<NCH1,128,0,stream>>>(dtp, xc1, B1, m1_Alog, m1_dt_w, m1_dt_b, aggA, aggB);
  k_carry<NCH1><<<16,1024,0,stream>>>(aggA, aggB, carry, 1024);
  k_pass2<64,8,2,LCH1><<<NCH1,128,0,stream>>>(dtp, xc1, B1, C1, z1, m1_Alog, m1_dt_w, m1_dt_b, m1_D, carry, yg1);
  // z1 dead -> zero bf16 conv-input halo region (covers both stages' halos)
  k_zero<<<(16*PCH+255)/256,256,0,stream>>>((float*)bfin, 16*PCH);
  k_outproj<32,64,0><<<dim3(576,2),dim3(64,4),0,stream>>>(yg1, m1_out_w, l, s,
                                                          stats1, bn1_g, bn1_b, bfin);
  k_conv_mfma<32><<<576,256,0,stream>>>(bfin, wA1, c1_b, conv1raw);
  k_bn_reduce<<<dim3(16,8),256,0,stream>>>(conv1raw, stats1);

  // ================= stage 2: mamba(dim=16, di=32) + conv2 + bn2 =================
  k_inproj<16,32,true,8><<<dim3(576,2),dim3(64,4),0,stream>>>(conv1raw, conv1raw, stats1, bn1_g, bn1_b,
                                                              m2_ln_w, m2_ln_b, m2_in_w, xs2, z2);
  k_dwconv<32><<<1152,256,0,stream>>>(xs2, m2_cw, m2_cb, xc2);
  k_xproj<32,1><<<dim3(576,3),dim3(64,4),0,stream>>>(xc2, m2_xp_w, dtp, B1, C1);
  k_pass1<32,4,1,LCH2><<<NCH2,128,0,stream>>>(dtp, xc2, B1, m2_Alog, m2_dt_w, m2_dt_b, aggA, aggB);
  k_carry<NCH2><<<8,1024,0,stream>>>(aggA, aggB, carry, 512);
  k_pass2<32,4,1,LCH2><<<NCH2,128,0,stream>>>(dtp, xc2, B1, C1, z2, m2_Alog, m2_dt_w, m2_dt_b, m2_D, carry, yg2);
  // halo of bfin (ch 0..15) is still zero from stage-1 fill; only interiors rewritten
  k_outproj<16,32,1><<<dim3(576,1),dim3(64,4),0,stream>>>(yg2, m2_out_w, conv1raw, conv1raw,
                                                          stats1, bn1_g, bn1_b, bfin);
  k_conv_mfma<16><<<576,256,0,stream>>>(bfin, wA2, c2_b, conv2raw);
  k_bn_reduce<<<dim3(16,8),256,0,stream>>>(conv2raw, stats2);
  k_bn_norm4<<<576,256,0,stream>>>(conv2raw, stats2, bn2_g, bn2_b, (float*)d_out);
}